// Round 7
// baseline (156.461 us; speedup 1.0000x reference)
//
#include <hip/hip_runtime.h>

// GNN encoder, B=256, N=32, F=256, fully-connected edges, 2 passes.
// bf16 MFMA 16x16x32, fp32 accum.
// v8: full-K LDS tiles, ONE barrier per block. A staged (gemm128) or built
// (edge_fused) fully, then an uninterrupted 8x(k-step) MFMA streak with
// B-fragments streamed from the L2-resident swizzled weight image.
// 64KB LDS/block -> 2 blocks/CU; phases desync and overlap across blocks.

typedef short bf16x8 __attribute__((ext_vector_type(8)));
typedef float f32x4 __attribute__((ext_vector_type(4)));
typedef unsigned short ushort_t;

__device__ __forceinline__ unsigned short f2bf(float f) {
    unsigned u = __float_as_uint(f);
    u += 0x7fff + ((u >> 16) & 1);   // RNE
    return (unsigned short)(u >> 16);
}
__device__ __forceinline__ float lo16f(unsigned w) { return __uint_as_float(w << 16); }
__device__ __forceinline__ float hi16f(unsigned w) { return __uint_as_float(w & 0xffff0000u); }
__device__ __forceinline__ unsigned cvt_pk_bf16(float lo, float hi) {
    unsigned r;
    asm volatile("v_cvt_pk_bf16_f32 %0, %1, %2" : "=v"(r) : "v"(lo), "v"(hi));
    return r;
}
__device__ __forceinline__ void gload16(const void* g, void* l) {
    __builtin_amdgcn_global_load_lds(
        (const __attribute__((address_space(1))) void*)g,
        (__attribute__((address_space(3))) void*)l, 16, 0, 0);
}

// ---------------------------------------------------------------------------
// Weight prep: logical Wt[n][k] -> swizzled image:
// idx = kb*8192 + n*32 + (kc ^ ((n>>1)&3))*8 + (k&7), kb=k>>5, kc=(k>>3)&3.
__global__ __launch_bounds__(256) void prep_weights(
    const float* __restrict__ w_in1, const float* __restrict__ w_in2,
    const float* __restrict__ w_e1,  const float* __restrict__ w_e2,
    const float* __restrict__ w_n1,  const float* __restrict__ w_n2,
    ushort_t* __restrict__ dst)
{
    __shared__ ushort_t tile[32][264];
    const int wid = blockIdx.x >> 3;   // 0..6
    const int kb  = blockIdx.x & 7;
    const float* src;
    switch (wid) {
        case 0: src = w_in1; break;
        case 1: src = w_in2; break;
        case 2: src = w_e1; break;              // top half (send side)
        case 3: src = w_e1 + 65536; break;      // bottom half (recv side)
        case 4: src = w_e2; break;
        case 5: src = w_n1; break;
        default: src = w_n2; break;
    }
    const int t = threadIdx.x;
#pragma unroll
    for (int k0 = 0; k0 < 32; k0++)
        tile[k0][t] = f2bf(src[(size_t)(kb * 32 + k0) * 256 + t]);  // coalesced
    __syncthreads();
    ushort_t* base = dst + wid * 65536 + kb * 8192 + t * 32;
    const int sw = (t >> 1) & 3;
#pragma unroll
    for (int kc = 0; kc < 4; kc++) {
        union { uint4 q; ushort_t u[8]; } w;
#pragma unroll
        for (int ko = 0; ko < 8; ko++) w.u[ko] = tile[kc * 8 + ko][t];
        *(uint4*)&base[(kc ^ sw) * 8] = w.q;
    }
}

// x fp32 -> bf16
__global__ __launch_bounds__(256) void conv_x(
    const float* __restrict__ x, ushort_t* __restrict__ xb, int n8)
{
    int i = blockIdx.x * 256 + threadIdx.x;
    if (i >= n8) return;
    const float4* p = (const float4*)x + (size_t)i * 2;
    float4 a = p[0], b = p[1];
    ushort4 o0 = make_ushort4(f2bf(a.x), f2bf(a.y), f2bf(a.z), f2bf(a.w));
    ushort4 o1 = make_ushort4(f2bf(b.x), f2bf(b.y), f2bf(b.z), f2bf(b.w));
    ((ushort4*)xb)[(size_t)i * 2]     = o0;
    ((ushort4*)xb)[(size_t)i * 2 + 1] = o1;
}

// ---------------------------------------------------------------------------
// Direct GEMM v2: block = 128 rows x 64 cols, 4 waves (wave = 32 rows x 64).
// Full-K A tile (64KB) staged via 16 pre-swizzled gload16/thread, ONE barrier,
// then 8 k-steps of ds_read + MFMA with B-frags streamed from L2 image.
// A LDS layout: ushort off = r*256 + ((kc ^ (r&7))*8) + (k&7), kc = k>>3.
// split: blockIdx.y >= split -> second weight image (WB+65536), null bias,
// output cols offset 256 (merged U'/V dispatch).
// EPI: 2 bias+relu bf16, 3 bias+relu f32, 4 bias(optional) no-relu bf16
template <int EPI>
__global__ __launch_bounds__(256, 2) void gemm128(
    const ushort_t* __restrict__ A, const ushort_t* __restrict__ WB,
    const float* __restrict__ bias, void* __restrict__ out, int ldc, int split)
{
    __shared__ ushort_t As[128 * 256];   // 64KB

    const int mb = (blockIdx.x & 7) * 8 + (blockIdx.x >> 3);  // 64 blocks, XCD swz
    const int m0 = mb * 128;
    const int ny = blockIdx.y;
    int nloc; const ushort_t* wb; const float* bp; int nout;
    if (ny >= split) { nloc = (ny - split) * 64; wb = WB + 65536; bp = nullptr; nout = 256 + nloc; }
    else             { nloc = ny * 64;           wb = WB;         bp = bias;    nout = nloc; }

    const int t = threadIdx.x;
    const int lane = t & 63;
    const int w = t >> 6;
    const int lr = lane & 15, lg = lane >> 4;

    // ---- stage A (pre-swizzled source, linear LDS dest): q = i*256+w*64+lane
    {
        const int r0  = w * 2 + (lane >> 5);
        const int kcp = lane & 31;
        const ushort_t* src = A + (size_t)(m0 + r0) * 256 + ((kcp ^ (r0 & 7)) * 8);
        ushort_t* dst = &As[w * 512];
#pragma unroll
        for (int i = 0; i < 16; i++)
            gload16(src + i * 2048, dst + i * 2048);   // +8 rows per iter
    }

    // ---- B fragment offsets in weight image + bias
    int boffs[4]; float bv[4];
#pragma unroll
    for (int fn = 0; fn < 4; fn++) {
        const int n = nloc + fn * 16 + lr;
        boffs[fn] = n * 32 + ((lg ^ ((n >> 1) & 3)) * 8);
        bv[fn] = bp ? bp[n] : 0.f;
    }
    // A fragment bases
    int abase[2], asw[2];
#pragma unroll
    for (int fm = 0; fm < 2; fm++) {
        const int r = w * 32 + fm * 16 + lr;
        abase[fm] = r * 256;
        asw[fm] = r & 7;
    }

    bf16x8 bc[4];
#pragma unroll
    for (int fn = 0; fn < 4; fn++) bc[fn] = *(const bf16x8*)&wb[boffs[fn]];

    __syncthreads();   // (compiler drains gloads here)

    f32x4 acc[2][4] = {};
#pragma unroll
    for (int kb = 0; kb < 8; kb++) {
        bf16x8 bn[4];
        if (kb < 7)
#pragma unroll
            for (int fn = 0; fn < 4; fn++)
                bn[fn] = *(const bf16x8*)&wb[(kb + 1) * 8192 + boffs[fn]];
        bf16x8 af[2];
#pragma unroll
        for (int fm = 0; fm < 2; fm++)
            af[fm] = *(const bf16x8*)&As[abase[fm] + (((kb * 4 + lg) ^ asw[fm]) * 8)];
#pragma unroll
        for (int fm = 0; fm < 2; fm++)
#pragma unroll
            for (int fn = 0; fn < 4; fn++)
                acc[fm][fn] = __builtin_amdgcn_mfma_f32_16x16x32_bf16(
                    af[fm], bc[fn], acc[fm][fn], 0, 0, 0);
        if (kb < 7)
#pragma unroll
            for (int fn = 0; fn < 4; fn++) bc[fn] = bn[fn];
    }

#pragma unroll
    for (int fm = 0; fm < 2; fm++)
#pragma unroll
        for (int fn = 0; fn < 4; fn++) {
            const int col = nout + fn * 16 + lr;
#pragma unroll
            for (int r = 0; r < 4; r++) {
                const int row = m0 + w * 32 + fm * 16 + lg * 4 + r;
                float v = acc[fm][fn][r] + bv[fn];
                if constexpr (EPI == 2 || EPI == 3) v = fmaxf(v, 0.f);
                if constexpr (EPI == 3)
                    ((float*)out)[(size_t)row * ldc + col] = v;
                else
                    ((ushort_t*)out)[(size_t)row * ldc + col] = f2bf(v);
            }
        }
}

// ---------------------------------------------------------------------------
// Fused edge layer-2 + scatter-mean, v8: full-K edge tile, one barrier.
// Grid 2048 x 256 thr (4 waves). Block = (batch, quad of 4 receivers):
// 128 virtual rows (4 recv x 32 slots, slot31 dummy) x full K=256.
// Build phase: each thread builds one half-row (128 k) of relu(U'+V) into
// the swizzled 64KB LDS tile. One barrier. Then 8 k-steps x 32 MFMA/wave
// (wave tile 128x64), B-frags prefetched from L2 image, setprio around MFMA.
__global__ __launch_bounds__(256, 2) void edge_fused(
    const ushort_t* __restrict__ UVb,   // [8192][512] bf16: U'(+b_e1) | V
    const ushort_t* __restrict__ WBsw,  // swizzled w_e2 image
    const float* __restrict__ b2,
    ushort_t* __restrict__ agg)         // [8192][256] bf16
{
    __shared__ ushort_t As[128 * 256];  // 64KB

    const int logical = (blockIdx.x & 7) * 256 + (blockIdx.x >> 3);  // 2048%8==0
    const int bb = logical >> 3;        // batch
    const int g0 = (logical & 7) * 4;   // first receiver of the quad
    const int t = threadIdx.x;
    const int lane = t & 63;
    const int w = t >> 6;
    const int lr = lane & 15, lg = lane >> 4;

    // ---- build mapping: thread -> (row, k-half)
    const int br = t >> 1;              // row 0..127
    const int h  = t & 1;               // k half (128 elems)
    const int jr = br >> 5;
    const int s  = br & 31;
    const int j  = g0 + jr;
    const int si = (s == 31) ? j : (s + (s >= j ? 1 : 0));
    const ushort_t* up = UVb + (size_t)(bb * 32 + si) * 512 + h * 128;
    const ushort_t* vp = UVb + (size_t)(bb * 32 + j) * 512 + 256 + h * 128;
    ushort_t* aw = &As[br * 256];
    const int bsw = br & 7;

    // ---- build full half-row: 16 chunks of 8 elems
#pragma unroll
    for (int i = 0; i < 16; i++) {
        uint4 u = *(const uint4*)(up + i * 8);
        uint4 v = *(const uint4*)(vp + i * 8);
        uint4 q;
        q.x = cvt_pk_bf16(fmaxf(lo16f(u.x) + lo16f(v.x), 0.f), fmaxf(hi16f(u.x) + hi16f(v.x), 0.f));
        q.y = cvt_pk_bf16(fmaxf(lo16f(u.y) + lo16f(v.y), 0.f), fmaxf(hi16f(u.y) + hi16f(v.y), 0.f));
        q.z = cvt_pk_bf16(fmaxf(lo16f(u.z) + lo16f(v.z), 0.f), fmaxf(hi16f(u.z) + hi16f(v.z), 0.f));
        q.w = cvt_pk_bf16(fmaxf(lo16f(u.w) + lo16f(v.w), 0.f), fmaxf(hi16f(u.w) + hi16f(v.w), 0.f));
        *(uint4*)&aw[((h * 16 + i) ^ bsw) * 8] = q;
    }

    // ---- MFMA-side constants
    int abase[8], asw[8];
#pragma unroll
    for (int m = 0; m < 8; m++) {
        const int r = m * 16 + lr;
        abase[m] = r * 256;
        asw[m] = r & 7;
    }
    int boffs[4]; float bv[4];
#pragma unroll
    for (int fn = 0; fn < 4; fn++) {
        const int n = w * 64 + fn * 16 + lr;
        boffs[fn] = n * 32 + ((lg ^ ((n >> 1) & 3)) * 8);
        bv[fn] = b2[n];
    }
    bf16x8 bc[4];
#pragma unroll
    for (int fn = 0; fn < 4; fn++) bc[fn] = *(const bf16x8*)&WBsw[boffs[fn]];

    __syncthreads();

    f32x4 acc[8][4] = {};
#pragma unroll
    for (int kb = 0; kb < 8; kb++) {
        bf16x8 bn[4];
        if (kb < 7)
#pragma unroll
            for (int fn = 0; fn < 4; fn++)
                bn[fn] = *(const bf16x8*)&WBsw[(kb + 1) * 8192 + boffs[fn]];
        bf16x8 af[8];
#pragma unroll
        for (int m = 0; m < 8; m++)
            af[m] = *(const bf16x8*)&As[abase[m] + (((kb * 4 + lg) ^ asw[m]) * 8)];
        __builtin_amdgcn_s_setprio(1);
#pragma unroll
        for (int fn = 0; fn < 4; fn++)
#pragma unroll
            for (int m = 0; m < 8; m++)
                acc[m][fn] = __builtin_amdgcn_mfma_f32_16x16x32_bf16(
                    af[m], bc[fn], acc[m][fn], 0, 0, 0);
        __builtin_amdgcn_s_setprio(0);
        if (kb < 7)
#pragma unroll
            for (int fn = 0; fn < 4; fn++) bc[fn] = bn[fn];
    }

    // ---- Epilogue: bias+relu, sum 31 real slots per receiver, /31, bf16 out.
#pragma unroll
    for (int fn = 0; fn < 4; fn++) {
        const int col = w * 64 + fn * 16 + lr;
#pragma unroll
        for (int recv = 0; recv < 4; recv++) {
            float sum = 0.f;
#pragma unroll
            for (int q = 0; q < 2; q++) {
                const int fm = recv * 2 + q;
#pragma unroll
                for (int r = 0; r < 4; r++) {
                    float v = fmaxf(acc[fm][fn][r] + bv[fn], 0.f);
                    if (!(q == 1 && lg == 3 && r == 3)) sum += v;  // skip slot 31
                }
            }
            sum += __shfl_xor(sum, 16);
            sum += __shfl_xor(sum, 32);
            if (lane < 16)
                agg[(size_t)(bb * 32 + g0 + recv) * 256 + col] = f2bf(sum * (1.0f / 31.0f));
        }
    }
}

// ---------------------------------------------------------------------------
extern "C" void kernel_launch(void* const* d_in, const int* in_sizes, int n_in,
                              void* d_out, int out_size, void* d_ws, size_t ws_size,
                              hipStream_t stream)
{
    const float* x     = (const float*)d_in[0];
    const float* w_in1 = (const float*)d_in[3];
    const float* b_in1 = (const float*)d_in[4];
    const float* w_in2 = (const float*)d_in[5];
    const float* b_in2 = (const float*)d_in[6];
    const float* w_e1  = (const float*)d_in[7];
    const float* b_e1  = (const float*)d_in[8];
    const float* w_e2  = (const float*)d_in[9];
    const float* b_e2  = (const float*)d_in[10];
    const float* w_n1  = (const float*)d_in[11];
    const float* b_n1  = (const float*)d_in[12];
    const float* w_n2  = (const float*)d_in[13];
    const float* b_n2  = (const float*)d_in[14];

    char* ws = (char*)d_ws;
    size_t off = 0;
    auto alloc = [&](size_t n) { char* p = ws + off; off += (n + 255) & ~(size_t)255; return p; };

    ushort_t* wt  = (ushort_t*)alloc(7 * 65536 * sizeof(ushort_t));
    ushort_t* xb  = (ushort_t*)alloc(8192 * 256 * 2);
    ushort_t* h   = (ushort_t*)alloc(8192 * 256 * 2);
    ushort_t* t1  = (ushort_t*)alloc(8192 * 256 * 2);
    ushort_t* UVb = (ushort_t*)alloc(8192 * 512 * 2);
    ushort_t* ag  = (ushort_t*)alloc(8192 * 256 * 2);
    (void)ws_size; (void)in_sizes; (void)n_in; (void)out_size;

    prep_weights<<<56, 256, 0, stream>>>(w_in1, w_in2, w_e1, w_e2, w_n1, w_n2, wt);
    conv_x<<<1024, 256, 0, stream>>>(x, xb, 262144);

    dim3 gs(64, 4);
    gemm128<2><<<gs, 256, 0, stream>>>(xb, wt + 0 * 65536, b_in1, t1, 256, 99);
    gemm128<2><<<gs, 256, 0, stream>>>(t1, wt + 1 * 65536, b_in2, h, 256, 99);

    for (int p = 0; p < 2; p++) {
        // U' = h@We1_top + b_e1, V = h@We1_bot — one dispatch (split=4), bf16 out
        dim3 guv(64, 8);
        gemm128<4><<<guv, 256, 0, stream>>>(h, wt + 2 * 65536, b_e1, UVb, 512, 4);
        edge_fused<<<2048, 256, 0, stream>>>(UVb, wt + 4 * 65536, b_e2, ag);
        gemm128<2><<<gs, 256, 0, stream>>>(ag, wt + 5 * 65536, b_n1, t1, 256, 99);
        if (p == 0)
            gemm128<2><<<gs, 256, 0, stream>>>(t1, wt + 6 * 65536, b_n2, h, 256, 99);
        else
            gemm128<3><<<gs, 256, 0, stream>>>(t1, wt + 6 * 65536, b_n2, (float*)d_out, 256, 99);
    }
}

// Round 8
// 135.646 us; speedup vs baseline: 1.1535x; 1.1535x over previous
//
#include <hip/hip_runtime.h>

// GNN encoder, B=256, N=32, F=256, fully-connected edges, 2 passes.
// bf16 MFMA 16x16x32, fp32 accum.
// R8: fused MLP chains (swapped-operand MFMA for cheap layer handoff) +
// v7 edge kernel (best measured) with setprio around the MFMA cluster.
// 7 dispatches total: prep, conv, mlp3(in), edge, mlp3(node), edge, mlp2(fin).

typedef short bf16x8 __attribute__((ext_vector_type(8)));
typedef float f32x4 __attribute__((ext_vector_type(4)));
typedef unsigned short ushort_t;

__device__ __forceinline__ unsigned short f2bf(float f) {
    unsigned u = __float_as_uint(f);
    u += 0x7fff + ((u >> 16) & 1);   // RNE
    return (unsigned short)(u >> 16);
}
__device__ __forceinline__ float lo16f(unsigned w) { return __uint_as_float(w << 16); }
__device__ __forceinline__ float hi16f(unsigned w) { return __uint_as_float(w & 0xffff0000u); }
__device__ __forceinline__ unsigned cvt_pk_bf16(float lo, float hi) {
    unsigned r;
    asm volatile("v_cvt_pk_bf16_f32 %0, %1, %2" : "=v"(r) : "v"(lo), "v"(hi));
    return r;
}
__device__ __forceinline__ void gload16(const void* g, void* l) {
    __builtin_amdgcn_global_load_lds(
        (const __attribute__((address_space(1))) void*)g,
        (__attribute__((address_space(3))) void*)l, 16, 0, 0);
}

// ---------------------------------------------------------------------------
// Weight prep: logical Wt[n][k] -> swizzled image:
// idx = kb*8192 + n*32 + (kc ^ ((n>>1)&3))*8 + (k&7), kb=k>>5, kc=(k>>3)&3.
__global__ __launch_bounds__(256) void prep_weights(
    const float* __restrict__ w_in1, const float* __restrict__ w_in2,
    const float* __restrict__ w_e1,  const float* __restrict__ w_e2,
    const float* __restrict__ w_n1,  const float* __restrict__ w_n2,
    ushort_t* __restrict__ dst)
{
    __shared__ ushort_t tile[32][264];
    const int wid = blockIdx.x >> 3;   // 0..6
    const int kb  = blockIdx.x & 7;
    const float* src;
    switch (wid) {
        case 0: src = w_in1; break;
        case 1: src = w_in2; break;
        case 2: src = w_e1; break;              // top half (send side)
        case 3: src = w_e1 + 65536; break;      // bottom half (recv side)
        case 4: src = w_e2; break;
        case 5: src = w_n1; break;
        default: src = w_n2; break;
    }
    const int t = threadIdx.x;
#pragma unroll
    for (int k0 = 0; k0 < 32; k0++)
        tile[k0][t] = f2bf(src[(size_t)(kb * 32 + k0) * 256 + t]);  // coalesced
    __syncthreads();
    ushort_t* base = dst + wid * 65536 + kb * 8192 + t * 32;
    const int sw = (t >> 1) & 3;
#pragma unroll
    for (int kc = 0; kc < 4; kc++) {
        union { uint4 q; ushort_t u[8]; } w;
#pragma unroll
        for (int ko = 0; ko < 8; ko++) w.u[ko] = tile[kc * 8 + ko][t];
        *(uint4*)&base[(kc ^ sw) * 8] = w.q;
    }
}

// x fp32 -> bf16
__global__ __launch_bounds__(256) void conv_x(
    const float* __restrict__ x, ushort_t* __restrict__ xb, int n8)
{
    int i = blockIdx.x * 256 + threadIdx.x;
    if (i >= n8) return;
    const float4* p = (const float4*)x + (size_t)i * 2;
    float4 a = p[0], b = p[1];
    ushort4 o0 = make_ushort4(f2bf(a.x), f2bf(a.y), f2bf(a.z), f2bf(a.w));
    ushort4 o1 = make_ushort4(f2bf(b.x), f2bf(b.y), f2bf(b.z), f2bf(b.w));
    ((ushort4*)xb)[(size_t)i * 2]     = o0;
    ((ushort4*)xb)[(size_t)i * 2 + 1] = o1;
}

// ---------------------------------------------------------------------------
// Fused MLP chain. Block = 32 rows, 4 waves (wave owns a 64-col slice).
// A-tiles [32][256] bf16 in LDS, XOR chunk swizzle: elem off =
//   r*256 + ((kc ^ (r&7))*8) + (k&7), kc = k>>3.
// Swapped MFMA: acc = mfma(Wfrag, Xfrag) -> D[row=n (reg), col=m (lane&15)],
// so each lane holds 4 k-contiguous outputs -> b64 LDS writes for handoff.

// one hidden layer: A(src LDS) @ W -> relu(+bias) -> Ad (LDS)
__device__ __forceinline__ void layer_to_lds(
    const ushort_t* __restrict__ wimg, const float* __restrict__ bias,
    const ushort_t* __restrict__ As, ushort_t* __restrict__ Ad,
    const int w, const int lr, const int lg)
{
    int boffs[4]; float4 b4[4];
#pragma unroll
    for (int fn = 0; fn < 4; fn++) {
        const int n = w * 64 + fn * 16 + lr;
        boffs[fn] = n * 32 + ((lg ^ ((n >> 1) & 3)) * 8);
        b4[fn] = *(const float4*)&bias[w * 64 + fn * 16 + lg * 4];
    }
    bf16x8 bc[4];
#pragma unroll
    for (int fn = 0; fn < 4; fn++) bc[fn] = *(const bf16x8*)&wimg[boffs[fn]];
    f32x4 acc[4][2] = {};
#pragma unroll
    for (int kb = 0; kb < 8; kb++) {
        bf16x8 bn[4];
        if (kb < 7)
#pragma unroll
            for (int fn = 0; fn < 4; fn++)
                bn[fn] = *(const bf16x8*)&wimg[(kb + 1) * 8192 + boffs[fn]];
        bf16x8 af[2];
#pragma unroll
        for (int fm = 0; fm < 2; fm++) {
            const int r = fm * 16 + lr;
            af[fm] = *(const bf16x8*)&As[r * 256 + (((kb * 4 + lg) ^ (r & 7)) * 8)];
        }
#pragma unroll
        for (int fn = 0; fn < 4; fn++)
#pragma unroll
            for (int fm = 0; fm < 2; fm++)
                acc[fn][fm] = __builtin_amdgcn_mfma_f32_16x16x32_bf16(
                    bc[fn], af[fm], acc[fn][fm], 0, 0, 0);
        if (kb < 7)
#pragma unroll
            for (int fn = 0; fn < 4; fn++) bc[fn] = bn[fn];
    }
#pragma unroll
    for (int fn = 0; fn < 4; fn++) {
        const int k0 = w * 64 + fn * 16 + lg * 4;     // output col = next-layer k
        const int kc = k0 >> 3, kj = k0 & 7;
#pragma unroll
        for (int fm = 0; fm < 2; fm++) {
            const int m = fm * 16 + lr;
            float v0 = fmaxf(acc[fn][fm][0] + b4[fn].x, 0.f);
            float v1 = fmaxf(acc[fn][fm][1] + b4[fn].y, 0.f);
            float v2 = fmaxf(acc[fn][fm][2] + b4[fn].z, 0.f);
            float v3 = fmaxf(acc[fn][fm][3] + b4[fn].w, 0.f);
            uint2 q = { cvt_pk_bf16(v0, v1), cvt_pk_bf16(v2, v3) };
            *(uint2*)&Ad[m * 256 + ((kc ^ (m & 7)) * 8) + kj] = q;
        }
    }
}

// e1 layer: A @ [W_top|W_bot] -> UVb[node][512] bf16 (U' = +b_e1, V raw; no relu)
__device__ __forceinline__ void layer_e1(
    const ushort_t* __restrict__ wE, const float* __restrict__ bE,
    const ushort_t* __restrict__ As, ushort_t* __restrict__ UVb,
    const int m0, const int w, const int lr, const int lg)
{
    const ushort_t* wimg = (w < 2) ? wE : (wE + 65536);
    const int nb = (w & 1) * 128;
    int boffs[8]; float4 b4[8];
#pragma unroll
    for (int fn = 0; fn < 8; fn++) {
        const int n = nb + fn * 16 + lr;
        boffs[fn] = n * 32 + ((lg ^ ((n >> 1) & 3)) * 8);
        if (w < 2) b4[fn] = *(const float4*)&bE[nb + fn * 16 + lg * 4];
        else       b4[fn] = make_float4(0.f, 0.f, 0.f, 0.f);
    }
    bf16x8 bc[8];
#pragma unroll
    for (int fn = 0; fn < 8; fn++) bc[fn] = *(const bf16x8*)&wimg[boffs[fn]];
    f32x4 acc[8][2] = {};
#pragma unroll
    for (int kb = 0; kb < 8; kb++) {
        bf16x8 bn[8];
        if (kb < 7)
#pragma unroll
            for (int fn = 0; fn < 8; fn++)
                bn[fn] = *(const bf16x8*)&wimg[(kb + 1) * 8192 + boffs[fn]];
        bf16x8 af[2];
#pragma unroll
        for (int fm = 0; fm < 2; fm++) {
            const int r = fm * 16 + lr;
            af[fm] = *(const bf16x8*)&As[r * 256 + (((kb * 4 + lg) ^ (r & 7)) * 8)];
        }
#pragma unroll
        for (int fn = 0; fn < 8; fn++)
#pragma unroll
            for (int fm = 0; fm < 2; fm++)
                acc[fn][fm] = __builtin_amdgcn_mfma_f32_16x16x32_bf16(
                    bc[fn], af[fm], acc[fn][fm], 0, 0, 0);
        if (kb < 7)
#pragma unroll
            for (int fn = 0; fn < 8; fn++) bc[fn] = bn[fn];
    }
#pragma unroll
    for (int fn = 0; fn < 8; fn++) {
        const int nglob = w * 128 + fn * 16 + lg * 4;
#pragma unroll
        for (int fm = 0; fm < 2; fm++) {
            const int node = m0 + fm * 16 + lr;
            float v0 = acc[fn][fm][0] + b4[fn].x;
            float v1 = acc[fn][fm][1] + b4[fn].y;
            float v2 = acc[fn][fm][2] + b4[fn].z;
            float v3 = acc[fn][fm][3] + b4[fn].w;
            uint2 q = { cvt_pk_bf16(v0, v1), cvt_pk_bf16(v2, v3) };
            *(uint2*)&UVb[(size_t)node * 512 + nglob] = q;
        }
    }
}

// final layer: A @ W -> relu(+bias) -> f32 out[8192][256]
__device__ __forceinline__ void layer_fin(
    const ushort_t* __restrict__ wimg, const float* __restrict__ bias,
    const ushort_t* __restrict__ As, float* __restrict__ out,
    const int m0, const int w, const int lr, const int lg)
{
    int boffs[4]; float4 b4[4];
#pragma unroll
    for (int fn = 0; fn < 4; fn++) {
        const int n = w * 64 + fn * 16 + lr;
        boffs[fn] = n * 32 + ((lg ^ ((n >> 1) & 3)) * 8);
        b4[fn] = *(const float4*)&bias[w * 64 + fn * 16 + lg * 4];
    }
    bf16x8 bc[4];
#pragma unroll
    for (int fn = 0; fn < 4; fn++) bc[fn] = *(const bf16x8*)&wimg[boffs[fn]];
    f32x4 acc[4][2] = {};
#pragma unroll
    for (int kb = 0; kb < 8; kb++) {
        bf16x8 bn[4];
        if (kb < 7)
#pragma unroll
            for (int fn = 0; fn < 4; fn++)
                bn[fn] = *(const bf16x8*)&wimg[(kb + 1) * 8192 + boffs[fn]];
        bf16x8 af[2];
#pragma unroll
        for (int fm = 0; fm < 2; fm++) {
            const int r = fm * 16 + lr;
            af[fm] = *(const bf16x8*)&As[r * 256 + (((kb * 4 + lg) ^ (r & 7)) * 8)];
        }
#pragma unroll
        for (int fn = 0; fn < 4; fn++)
#pragma unroll
            for (int fm = 0; fm < 2; fm++)
                acc[fn][fm] = __builtin_amdgcn_mfma_f32_16x16x32_bf16(
                    bc[fn], af[fm], acc[fn][fm], 0, 0, 0);
        if (kb < 7)
#pragma unroll
            for (int fn = 0; fn < 4; fn++) bc[fn] = bn[fn];
    }
#pragma unroll
    for (int fn = 0; fn < 4; fn++) {
        const int col = w * 64 + fn * 16 + lg * 4;
#pragma unroll
        for (int fm = 0; fm < 2; fm++) {
            const int row = m0 + fm * 16 + lr;
            float4 o;
            o.x = fmaxf(acc[fn][fm][0] + b4[fn].x, 0.f);
            o.y = fmaxf(acc[fn][fm][1] + b4[fn].y, 0.f);
            o.z = fmaxf(acc[fn][fm][2] + b4[fn].z, 0.f);
            o.w = fmaxf(acc[fn][fm][3] + b4[fn].w, 0.f);
            *(float4*)&out[(size_t)row * 256 + col] = o;
        }
    }
}

template <int THREE>
__global__ __launch_bounds__(256, 2) void mlp_chain(
    const ushort_t* __restrict__ in,
    const ushort_t* __restrict__ wA, const float* __restrict__ bA,
    const ushort_t* __restrict__ wB, const float* __restrict__ bB,
    const ushort_t* __restrict__ wE, const float* __restrict__ bE,
    void* __restrict__ out)
{
    __shared__ ushort_t A0[32 * 256];
    __shared__ ushort_t A1[32 * 256];
    const int m0 = blockIdx.x * 32;
    const int t = threadIdx.x;
    const int lane = t & 63, w = t >> 6;
    const int lr = lane & 15, lg = lane >> 4;

    // stage input tile (pre-swizzled source, linear LDS dest)
#pragma unroll
    for (int i = 0; i < 4; i++) {
        const int r = i * 8 + (t >> 5);
        const int p = t & 31;
        gload16(in + (size_t)(m0 + r) * 256 + ((p ^ (r & 7)) * 8), &A0[i * 2048 + t * 8]);
    }
    __syncthreads();

    layer_to_lds(wA, bA, A0, A1, w, lr, lg);
    __syncthreads();
    if constexpr (THREE) {
        layer_to_lds(wB, bB, A1, A0, w, lr, lg);
        __syncthreads();
        layer_e1(wE, bE, A0, (ushort_t*)out, m0, w, lr, lg);
    } else {
        layer_fin(wB, bB, A1, (float*)out, m0, w, lr, lg);
    }
}

// ---------------------------------------------------------------------------
// Fused edge layer-2 + scatter-mean (v7, best measured) + setprio.
// Grid 2048 x 256 thr (4 waves). Block = (batch, quad of 4 receivers):
// 128 virtual rows (4 recv x 32 slots, slot31 dummy) x N=256.
// Wave w owns cols [w*64, w*64+64): wave tile 128x64, acc[8][4].
__global__ __launch_bounds__(256, 2) void edge_fused(
    const ushort_t* __restrict__ UVb,   // [8192][512] bf16: U'(+b_e1) | V
    const ushort_t* __restrict__ WBsw,  // swizzled w_e2 image
    const float* __restrict__ b2,
    ushort_t* __restrict__ agg)         // [8192][256] bf16
{
    __shared__ ushort_t As[2][4096];    // 128 rows x 32 k each

    const int logical = (blockIdx.x & 7) * 256 + (blockIdx.x >> 3);  // 2048%8==0
    const int bb = logical >> 3;        // batch
    const int g0 = (logical & 7) * 4;   // first receiver of the quad
    const int t = threadIdx.x;
    const int lane = t & 63;
    const int w = t >> 6;
    const int lr = lane & 15, lg = lane >> 4;

    // ---- A-build mapping: thread -> (row, k-half). 2 threads per row.
    const int brow = t >> 1;            // 0..127
    const int kh = t & 1;               // which 16-k half
    const int jr = brow >> 5;           // receiver within quad
    const int s = brow & 31;            // slot
    const int j = g0 + jr;
    const int si = (s == 31) ? j : (s + (s >= j ? 1 : 0));
    const ushort_t* up = UVb + (size_t)(bb * 32 + si) * 512 + kh * 16;
    const ushort_t* vp = UVb + (size_t)(bb * 32 + j) * 512 + 256 + kh * 16;
    const int swz = (brow >> 1) & 3;
    const int aw0 = brow * 32 + (((kh * 2)     ^ swz) * 8);
    const int aw1 = brow * 32 + (((kh * 2 + 1) ^ swz) * 8);

    // ---- MFMA-side offsets
    int aoff[8];
#pragma unroll
    for (int m = 0; m < 8; m++) {
        const int r = m * 16 + lr;
        aoff[m] = r * 32 + ((lg ^ ((r >> 1) & 3)) * 8);
    }
    int boff[4];
#pragma unroll
    for (int fn = 0; fn < 4; fn++) {
        const int n = w * 64 + fn * 16 + lr;
        boff[fn] = n * 32 + ((lg ^ ((n >> 1) & 3)) * 8);
    }

    // ---- prologue: build k-tile 0, load B k-tile 0
    {
        uint4 ua = *(const uint4*)up,        ub = *(const uint4*)(up + 8);
        uint4 va = *(const uint4*)vp,        vb = *(const uint4*)(vp + 8);
        uint4 q0, q1;
        q0.x = cvt_pk_bf16(fmaxf(lo16f(ua.x) + lo16f(va.x), 0.f), fmaxf(hi16f(ua.x) + hi16f(va.x), 0.f));
        q0.y = cvt_pk_bf16(fmaxf(lo16f(ua.y) + lo16f(va.y), 0.f), fmaxf(hi16f(ua.y) + hi16f(va.y), 0.f));
        q0.z = cvt_pk_bf16(fmaxf(lo16f(ua.z) + lo16f(va.z), 0.f), fmaxf(hi16f(ua.z) + hi16f(va.z), 0.f));
        q0.w = cvt_pk_bf16(fmaxf(lo16f(ua.w) + lo16f(va.w), 0.f), fmaxf(hi16f(ua.w) + hi16f(va.w), 0.f));
        q1.x = cvt_pk_bf16(fmaxf(lo16f(ub.x) + lo16f(vb.x), 0.f), fmaxf(hi16f(ub.x) + hi16f(vb.x), 0.f));
        q1.y = cvt_pk_bf16(fmaxf(lo16f(ub.y) + lo16f(vb.y), 0.f), fmaxf(hi16f(ub.y) + hi16f(vb.y), 0.f));
        q1.z = cvt_pk_bf16(fmaxf(lo16f(ub.z) + lo16f(vb.z), 0.f), fmaxf(hi16f(ub.z) + hi16f(vb.z), 0.f));
        q1.w = cvt_pk_bf16(fmaxf(lo16f(ub.w) + lo16f(vb.w), 0.f), fmaxf(hi16f(ub.w) + hi16f(vb.w), 0.f));
        *(uint4*)&As[0][aw0] = q0;
        *(uint4*)&As[0][aw1] = q1;
    }
    bf16x8 bc[4];
#pragma unroll
    for (int fn = 0; fn < 4; fn++) bc[fn] = *(const bf16x8*)&WBsw[boff[fn]];

    f32x4 acc[8][4] = {};

#pragma unroll
    for (int kb = 0; kb < 8; kb++) {
        __syncthreads();                      // As[kb&1] ready
        // prefetch next-step inputs (hidden under this step's MFMAs)
        uint4 ua, ub, va, vb;
        bf16x8 bn[4];
        if (kb < 7) {
            const ushort_t* upn = up + (kb + 1) * 32;
            const ushort_t* vpn = vp + (kb + 1) * 32;
            ua = *(const uint4*)upn;  ub = *(const uint4*)(upn + 8);
            va = *(const uint4*)vpn;  vb = *(const uint4*)(vpn + 8);
#pragma unroll
            for (int fn = 0; fn < 4; fn++)
                bn[fn] = *(const bf16x8*)&WBsw[(kb + 1) * 8192 + boff[fn]];
        }
        // MFMA on current tile
        bf16x8 af[8];
#pragma unroll
        for (int m = 0; m < 8; m++) af[m] = *(const bf16x8*)&As[kb & 1][aoff[m]];
        __builtin_amdgcn_s_setprio(1);
#pragma unroll
        for (int fn = 0; fn < 4; fn++)
#pragma unroll
            for (int m = 0; m < 8; m++)
                acc[m][fn] = __builtin_amdgcn_mfma_f32_16x16x32_bf16(
                    af[m], bc[fn], acc[m][fn], 0, 0, 0);
        __builtin_amdgcn_s_setprio(0);
        // build next tile + rotate B
        if (kb < 7) {
            uint4 q0, q1;
            q0.x = cvt_pk_bf16(fmaxf(lo16f(ua.x) + lo16f(va.x), 0.f), fmaxf(hi16f(ua.x) + hi16f(va.x), 0.f));
            q0.y = cvt_pk_bf16(fmaxf(lo16f(ua.y) + lo16f(va.y), 0.f), fmaxf(hi16f(ua.y) + hi16f(va.y), 0.f));
            q0.z = cvt_pk_bf16(fmaxf(lo16f(ua.z) + lo16f(va.z), 0.f), fmaxf(hi16f(ua.z) + hi16f(va.z), 0.f));
            q0.w = cvt_pk_bf16(fmaxf(lo16f(ua.w) + lo16f(va.w), 0.f), fmaxf(hi16f(ua.w) + hi16f(va.w), 0.f));
            q1.x = cvt_pk_bf16(fmaxf(lo16f(ub.x) + lo16f(vb.x), 0.f), fmaxf(hi16f(ub.x) + hi16f(vb.x), 0.f));
            q1.y = cvt_pk_bf16(fmaxf(lo16f(ub.y) + lo16f(vb.y), 0.f), fmaxf(hi16f(ub.y) + hi16f(vb.y), 0.f));
            q1.z = cvt_pk_bf16(fmaxf(lo16f(ub.z) + lo16f(vb.z), 0.f), fmaxf(hi16f(ub.z) + hi16f(vb.z), 0.f));
            q1.w = cvt_pk_bf16(fmaxf(lo16f(ub.w) + lo16f(vb.w), 0.f), fmaxf(hi16f(ub.w) + hi16f(vb.w), 0.f));
            *(uint4*)&As[(kb + 1) & 1][aw0] = q0;
            *(uint4*)&As[(kb + 1) & 1][aw1] = q1;
#pragma unroll
            for (int fn = 0; fn < 4; fn++) bc[fn] = bn[fn];
        }
    }

    // ---- Epilogue: bias+relu, sum 31 real slots per receiver, /31, write bf16.
#pragma unroll
    for (int fn = 0; fn < 4; fn++) {
        const int col = w * 64 + fn * 16 + lr;
        const float bvf = b2[col];
#pragma unroll
        for (int recv = 0; recv < 4; recv++) {
            float sum = 0.f;
#pragma unroll
            for (int q = 0; q < 2; q++) {
                const int fm = recv * 2 + q;
#pragma unroll
                for (int r = 0; r < 4; r++) {
                    float v = fmaxf(acc[fm][fn][r] + bvf, 0.f);
                    if (!(q == 1 && lg == 3 && r == 3)) sum += v;  // skip slot 31
                }
            }
            sum += __shfl_xor(sum, 16);
            sum += __shfl_xor(sum, 32);
            if (lane < 16)
                agg[(size_t)(bb * 32 + g0 + recv) * 256 + col] = f2bf(sum * (1.0f / 31.0f));
        }
    }
}

// ---------------------------------------------------------------------------
extern "C" void kernel_launch(void* const* d_in, const int* in_sizes, int n_in,
                              void* d_out, int out_size, void* d_ws, size_t ws_size,
                              hipStream_t stream)
{
    const float* x     = (const float*)d_in[0];
    const float* w_in1 = (const float*)d_in[3];
    const float* b_in1 = (const float*)d_in[4];
    const float* w_in2 = (const float*)d_in[5];
    const float* b_in2 = (const float*)d_in[6];
    const float* w_e1  = (const float*)d_in[7];
    const float* b_e1  = (const float*)d_in[8];
    const float* w_e2  = (const float*)d_in[9];
    const float* b_e2  = (const float*)d_in[10];
    const float* w_n1  = (const float*)d_in[11];
    const float* b_n1  = (const float*)d_in[12];
    const float* w_n2  = (const float*)d_in[13];
    const float* b_n2  = (const float*)d_in[14];

    char* ws = (char*)d_ws;
    size_t off = 0;
    auto alloc = [&](size_t n) { char* p = ws + off; off += (n + 255) & ~(size_t)255; return p; };

    ushort_t* wt  = (ushort_t*)alloc(7 * 65536 * sizeof(ushort_t));
    ushort_t* xb  = (ushort_t*)alloc(8192 * 256 * 2);
    ushort_t* UVb = (ushort_t*)alloc(8192 * 512 * 2);
    ushort_t* ag  = (ushort_t*)alloc(8192 * 256 * 2);
    (void)ws_size; (void)in_sizes; (void)n_in; (void)out_size;

    prep_weights<<<56, 256, 0, stream>>>(w_in1, w_in2, w_e1, w_e2, w_n1, w_n2, wt);
    conv_x<<<1024, 256, 0, stream>>>(x, xb, 262144);

    // pass 0 front: in1 -> in2 -> e1
    mlp_chain<1><<<256, 256, 0, stream>>>(xb,
        wt + 0 * 65536, b_in1, wt + 1 * 65536, b_in2, wt + 2 * 65536, b_e1, UVb);
    edge_fused<<<2048, 256, 0, stream>>>(UVb, wt + 4 * 65536, b_e2, ag);
    // pass 1 front: n1 -> n2 -> e1
    mlp_chain<1><<<256, 256, 0, stream>>>(ag,
        wt + 5 * 65536, b_n1, wt + 6 * 65536, b_n2, wt + 2 * 65536, b_e1, UVb);
    edge_fused<<<2048, 256, 0, stream>>>(UVb, wt + 4 * 65536, b_e2, ag);
    // final: n1 -> n2 (f32 out)
    mlp_chain<0><<<256, 256, 0, stream>>>(ag,
        wt + 5 * 65536, b_n1, wt + 6 * 65536, b_n2, nullptr, nullptr, d_out);
}